// Round 6
// baseline (198.362 us; speedup 1.0000x reference)
//
#include <hip/hip_runtime.h>
#include <stdint.h>

typedef __attribute__((ext_vector_type(8))) short short8;
typedef __attribute__((ext_vector_type(16))) float floatx16;

__device__ inline unsigned short f2bf(float x) {
  union { float f; unsigned int u; } v; v.f = x;
  unsigned int r = v.u + 0x7FFFu + ((v.u >> 16) & 1u);  // RNE
  return (unsigned short)(r >> 16);
}

// ---------------------------------------------------------------------------
// pack_all:
//   blocks [0,4096):    A_bf16[4096][2048] = bf16([x | h])
//   blocks [4096,6144): Wt_perm[4096][2048] = bf16(W^T), row
//                       R = (h>>5)*128 + g*32 + (h&31)
//                       -> in a 128-row group, n-block j (32 rows) == gate j,
//                          col within block == h&31. GEMM reads LINEAR rows.
// ---------------------------------------------------------------------------
__global__ void pack_all(const float* __restrict__ x, const float* __restrict__ h,
                         const float* __restrict__ wi, const float* __restrict__ wh,
                         unsigned short* __restrict__ A,
                         unsigned short* __restrict__ Wt) {
  int bid = blockIdx.x;
  int t = threadIdx.x;
  if (bid < 4096) {
    int idx = bid * 256 + t;
    int row = idx >> 8;
    int kc  = (idx & 255) << 3;
    const float* src = (kc < 1024) ? (x + (size_t)row * 1024 + kc)
                                   : (h + (size_t)row * 1024 + (kc - 1024));
    float4 a = ((const float4*)src)[0];
    float4 b = ((const float4*)src)[1];
    uint4 o;
    o.x = f2bf(a.x) | ((unsigned)f2bf(a.y) << 16);
    o.y = f2bf(a.z) | ((unsigned)f2bf(a.w) << 16);
    o.z = f2bf(b.x) | ((unsigned)f2bf(b.y) << 16);
    o.w = f2bf(b.z) | ((unsigned)f2bf(b.w) << 16);
    *(uint4*)(A + (size_t)row * 2048 + kc) = o;
  } else {
    __shared__ float tile[64][65];
    int b2 = bid - 4096;
    int kt = b2 & 31;
    int nt = b2 >> 5;
    int k0 = kt << 6, n0 = nt << 6;
    const float* src = (k0 < 1024) ? (wi + (size_t)k0 * 4096)
                                   : (wh + (size_t)(k0 - 1024) * 4096);
    int c4 = (t & 15) << 2, rr = t >> 4;
#pragma unroll
    for (int p = 0; p < 4; ++p) {
      int kk = rr + p * 16;
      float4 v = *(const float4*)(src + (size_t)kk * 4096 + n0 + c4);
      tile[kk][c4 + 0] = v.x; tile[kk][c4 + 1] = v.y;
      tile[kk][c4 + 2] = v.z; tile[kk][c4 + 3] = v.w;
    }
    __syncthreads();
    int k8 = (t & 7) << 3, nn = t >> 3;
#pragma unroll
    for (int p = 0; p < 2; ++p) {
      int n = n0 + nn + p * 32;          // global N index (gate*1024 + h)
      int hh = n & 1023, g = n >> 10;
      int R = ((hh >> 5) << 7) + (g << 5) + (hh & 31);
      int nl = nn + p * 32;
      uint4 o;
      o.x = f2bf(tile[k8 + 0][nl]) | ((unsigned)f2bf(tile[k8 + 1][nl]) << 16);
      o.y = f2bf(tile[k8 + 2][nl]) | ((unsigned)f2bf(tile[k8 + 3][nl]) << 16);
      o.z = f2bf(tile[k8 + 4][nl]) | ((unsigned)f2bf(tile[k8 + 5][nl]) << 16);
      o.w = f2bf(tile[k8 + 6][nl]) | ((unsigned)f2bf(tile[k8 + 7][nl]) << 16);
      *(uint4*)(Wt + (size_t)R * 2048 + k0 + k8) = o;
    }
  }
}

// ---------------------------------------------------------------------------
// gemm_lstm: 256x128 block, 4 waves each 64m x 128n, MFMA 32x32x16 bf16.
//   - A tile (256x64k, 32 KB) read 1x from LDS, B tile (128x64k, 16 KB) 4x
//     -> 96 KB/iter for 2.1 MFLOP/wave-iter (25% less LDS traffic than R5)
//   - n-block j == gate j (permuted W): acc[mb][j] lane-local 4-gate fusion
//   - XOR-8 source-chunk swizzle (R4/R5-verified, 0 conflicts)
//   - 32 iters, 512 blocks: half the barrier count of R5
// C/D map (m74/m101): col=lane&31, row=(reg&3)+8*(reg>>2)+4*(lane>>5)
// A/B frag: row=lane&31, k-octet=(lane>>5)  [analog of verified 16x16 layout]
// ---------------------------------------------------------------------------
__device__ inline void gl_lds16(const void* g, void* l) {
  __builtin_amdgcn_global_load_lds(
      (const __attribute__((address_space(1))) void*)g,
      (__attribute__((address_space(3))) void*)l, 16, 0, 0);
}

__device__ inline float sigm(float x)  { return 1.0f / (1.0f + __expf(-x)); }
__device__ inline float tanhx(float x) { return 2.0f / (1.0f + __expf(-2.0f * x)) - 1.0f; }

__global__ void __launch_bounds__(256, 2) gemm_lstm(
    const unsigned short* __restrict__ A,
    const unsigned short* __restrict__ Bt,
    const float* __restrict__ ct,
    const float* __restrict__ bi,
    const float* __restrict__ bh,
    float* __restrict__ out) {
  constexpr int K = 2048;
  __shared__ char AsB[256 * 128];  // 256 rows x 64 bf16 (128 B) = 32 KB
  __shared__ char BsB[128 * 128];  // 128 rows x 128 B = 16 KB
  const int tid  = threadIdx.x;
  const int lane = tid & 63;
  const int wave = tid >> 6;            // 0..3 = m-slice
  const int m0 = blockIdx.y << 8;       // 256 rows
  const int h0 = blockIdx.x << 5;       // 32 h per block (n-tile = 128 = 4g x 32h)

  // epilogue lane mapping + bias preload (latency hidden by K-loop)
  const int el = lane & 31;             // h offset / C col
  const int h5 = (lane >> 5) << 2;      // +4 rows for upper lane half
  const int h  = h0 + el;
  float bias[4];
#pragma unroll
  for (int j = 0; j < 4; ++j) bias[j] = bi[j * 1024 + h] + bh[j * 1024 + h];

  // ---- staging: uniform base + one shared per-lane offset (saddr form) ----
  const int sr = tid >> 3;                              // 0..31
  const int cs = ((tid & 7) ^ (sr & 7)) << 4;           // XOR-swizzled chunk
  const unsigned voff = (unsigned)sr * 4096u + (unsigned)cs;
  const char* aBase = (const char*)A  + (size_t)m0 * 4096;          // row=4096B
  const char* bBase = (const char*)Bt + (size_t)(blockIdx.x << 7) * 4096;
  char* aD = AsB + tid * 16;
  char* bD = BsB + tid * 16;

  floatx16 acc[2][4] = {};
  // LDS fragment bases: A row = wave*64 + mb*32 + (lane&31); B row = j*32 + (lane&31)
  // chunk(kstep) = ((lane>>5) + 2*kstep) ^ (lane&7), loop-invariant per kstep
  const int lrow = lane & 31;
  const int key  = lane & 7;
  const int khalf = lane >> 5;
  const char* aF = AsB + (wave * 64 + lrow) * 128;
  const char* bF = BsB + lrow * 128;
  int koff[4];
#pragma unroll
  for (int ks4 = 0; ks4 < 4; ++ks4) koff[ks4] = ((khalf + 2 * ks4) ^ key) << 4;

  for (int ks = 0; ks < K; ks += 64) {
    const char* aIt = aBase + ks * 2;   // uniform
    const char* bIt = bBase + ks * 2;   // uniform
#pragma unroll
    for (int p = 0; p < 8; ++p) gl_lds16(aIt + p * 131072 + voff, aD + p * 4096);
#pragma unroll
    for (int p = 0; p < 4; ++p) gl_lds16(bIt + p * 131072 + voff, bD + p * 4096);
    __syncthreads();
#pragma unroll
    for (int kst = 0; kst < 4; ++kst) {
      short8 af[2], bfr[4];
#pragma unroll
      for (int mb = 0; mb < 2; ++mb) af[mb] = *(const short8*)(aF + mb * 4096 + koff[kst]);
#pragma unroll
      for (int j = 0; j < 4; ++j)    bfr[j] = *(const short8*)(bF + j * 4096 + koff[kst]);
#pragma unroll
      for (int mb = 0; mb < 2; ++mb)
#pragma unroll
        for (int j = 0; j < 4; ++j)
          acc[mb][j] = __builtin_amdgcn_mfma_f32_32x32x16_bf16(af[mb], bfr[j], acc[mb][j], 0, 0, 0);
    }
    __syncthreads();
  }

  // ---- fused LSTM epilogue ----
  // row(mb,rg) = m0 + wave*64 + mb*32 + (rg&3) + 8*(rg>>2) + h5
  const int rowbase = m0 + wave * 64 + h5;
  float cv[2][16];
#pragma unroll
  for (int mb = 0; mb < 2; ++mb)
#pragma unroll
    for (int rg = 0; rg < 16; ++rg) {
      int row = rowbase + mb * 32 + (rg & 3) + ((rg >> 2) << 3);
      cv[mb][rg] = ct[(size_t)row * 1024 + h];
    }
#pragma unroll
  for (int mb = 0; mb < 2; ++mb) {
#pragma unroll
    for (int rg = 0; rg < 16; ++rg) {
      int row = rowbase + mb * 32 + (rg & 3) + ((rg >> 2) << 3);
      size_t o = (size_t)row * 1024 + h;
      float iv = sigm(acc[mb][0][rg] + bias[0]);
      float fv = sigm(acc[mb][1][rg] + bias[1]);
      float gv = tanhx(acc[mb][2][rg] + bias[2]);
      float ov = sigm(acc[mb][3][rg] + bias[3]);
      float cn = fv * cv[mb][rg] + iv * gv;
      out[o] = ov * tanhx(cn);
      out[4194304 + o] = cn;
    }
  }
}

// ---------------------------------------------------------------------------
extern "C" void kernel_launch(void* const* d_in, const int* in_sizes, int n_in,
                              void* d_out, int out_size, void* d_ws, size_t ws_size,
                              hipStream_t stream) {
  const float* x  = (const float*)d_in[0];
  const float* ht = (const float*)d_in[1];
  const float* ct = (const float*)d_in[2];
  const float* wi = (const float*)d_in[3];
  const float* wh = (const float*)d_in[4];
  const float* bi = (const float*)d_in[5];
  const float* bh = (const float*)d_in[6];
  float* out = (float*)d_out;

  char* ws = (char*)d_ws;
  unsigned short* Abf = (unsigned short*)ws;                 // 16 MiB
  unsigned short* Wbf = (unsigned short*)(ws + (16u << 20)); // 16 MiB

  pack_all<<<6144, 256, 0, stream>>>(x, ht, wi, wh, Abf, Wbf);
  gemm_lstm<<<dim3(32, 16), 256, 0, stream>>>(Abf, Wbf, ct, bi, bh, out);
}

// Round 7
// 197.314 us; speedup vs baseline: 1.0053x; 1.0053x over previous
//
#include <hip/hip_runtime.h>
#include <stdint.h>

typedef __attribute__((ext_vector_type(8))) short short8;
typedef __attribute__((ext_vector_type(4))) float floatx4;

__device__ inline unsigned short f2bf(float x) {
  union { float f; unsigned int u; } v; v.f = x;
  unsigned int r = v.u + 0x7FFFu + ((v.u >> 16) & 1u);  // RNE
  return (unsigned short)(r >> 16);
}

// ---------------------------------------------------------------------------
// pack_all: one dispatch does both packs.
//   blocks [0,4096):    A_bf16[4096][2048] = bf16([x | h])
//   blocks [4096,6144): Wt_perm[4096][2048] = bf16(W^T) with gate-interleaved
//                       row index R = (h>>5)*128 + ((h>>4)&1)*64 + g*16 + (h&15)
//                       so the GEMM's B staging reads LINEAR rows while the
//                       epilogue gets j == gate.
// ---------------------------------------------------------------------------
__global__ void pack_all(const float* __restrict__ x, const float* __restrict__ h,
                         const float* __restrict__ wi, const float* __restrict__ wh,
                         unsigned short* __restrict__ A,
                         unsigned short* __restrict__ Wt) {
  int bid = blockIdx.x;
  int t = threadIdx.x;
  if (bid < 4096) {
    int idx = bid * 256 + t;
    int row = idx >> 8;
    int kc  = (idx & 255) << 3;
    const float* src = (kc < 1024) ? (x + (size_t)row * 1024 + kc)
                                   : (h + (size_t)row * 1024 + (kc - 1024));
    float4 a = ((const float4*)src)[0];
    float4 b = ((const float4*)src)[1];
    uint4 o;
    o.x = f2bf(a.x) | ((unsigned)f2bf(a.y) << 16);
    o.y = f2bf(a.z) | ((unsigned)f2bf(a.w) << 16);
    o.z = f2bf(b.x) | ((unsigned)f2bf(b.y) << 16);
    o.w = f2bf(b.z) | ((unsigned)f2bf(b.w) << 16);
    *(uint4*)(A + (size_t)row * 2048 + kc) = o;
  } else {
    __shared__ float tile[64][65];
    int b2 = bid - 4096;
    int kt = b2 & 31;
    int nt = b2 >> 5;
    int k0 = kt << 6, n0 = nt << 6;
    const float* src = (k0 < 1024) ? (wi + (size_t)k0 * 4096)
                                   : (wh + (size_t)(k0 - 1024) * 4096);
    int c4 = (t & 15) << 2, rr = t >> 4;
#pragma unroll
    for (int p = 0; p < 4; ++p) {
      int kk = rr + p * 16;
      float4 v = *(const float4*)(src + (size_t)kk * 4096 + n0 + c4);
      tile[kk][c4 + 0] = v.x; tile[kk][c4 + 1] = v.y;
      tile[kk][c4 + 2] = v.z; tile[kk][c4 + 3] = v.w;
    }
    __syncthreads();
    int k8 = (t & 7) << 3, nn = t >> 3;
#pragma unroll
    for (int p = 0; p < 2; ++p) {
      int n = n0 + nn + p * 32;          // global N index (gate*1024 + h)
      int hh = n & 1023, g = n >> 10;
      int R = ((hh >> 5) << 7) + (((hh >> 4) & 1) << 6) + (g << 4) + (hh & 15);
      int nl = nn + p * 32;
      uint4 o;
      o.x = f2bf(tile[k8 + 0][nl]) | ((unsigned)f2bf(tile[k8 + 1][nl]) << 16);
      o.y = f2bf(tile[k8 + 2][nl]) | ((unsigned)f2bf(tile[k8 + 3][nl]) << 16);
      o.z = f2bf(tile[k8 + 4][nl]) | ((unsigned)f2bf(tile[k8 + 5][nl]) << 16);
      o.w = f2bf(tile[k8 + 6][nl]) | ((unsigned)f2bf(tile[k8 + 7][nl]) << 16);
      *(uint4*)(Wt + (size_t)R * 2048 + k0 + k8) = o;
    }
  }
}

// ---------------------------------------------------------------------------
// gemm_lstm: R5 structure (best known: 75.5 us) + XCD-aware grid swizzle.
// BK=64, XOR-8 source-chunk swizzle (0 conflicts, R4/R5-verified), saddr-form
// staging, hoisted LDS frag bases, launch_bounds(256,3) -> 3 blocks/CU.
// Grid: 1024 linear blocks; decode so id%8 (XCD under round-robin dispatch)
// owns a fixed 4-wide n-band (2 MB of B pinned in its L2) and walks 4x4
// superclusters sharing 4 A-row-slices + 4 B-col-slices.
// ---------------------------------------------------------------------------
__device__ inline void gl_lds16(const void* g, void* l) {
  __builtin_amdgcn_global_load_lds(
      (const __attribute__((address_space(1))) void*)g,
      (__attribute__((address_space(3))) void*)l, 16, 0, 0);
}

__device__ inline float sigm(float x)  { return 1.0f / (1.0f + __expf(-x)); }
__device__ inline float tanhx(float x) { return 2.0f / (1.0f + __expf(-2.0f * x)) - 1.0f; }

__global__ void __launch_bounds__(256, 3) gemm_lstm(
    const unsigned short* __restrict__ A,
    const unsigned short* __restrict__ Bt,
    const float* __restrict__ ct,
    const float* __restrict__ bi,
    const float* __restrict__ bh,
    float* __restrict__ out) {
  constexpr int K = 2048;
  __shared__ char AsB[128 * 128];  // 128 rows x 64 bf16 (128 B)
  __shared__ char BsB[128 * 128];
  const int tid  = threadIdx.x;
  const int lane = tid & 63;
  const int wave = tid >> 6;
  const int wm = wave >> 1, wn = wave & 1;

  // ---- XCD supertile swizzle (bijection on [0,1024)) ----
  // g = id%8 -> XCD band; s = id/8; bx = g*4 + (s&3); by = (s>>4)*4 + ((s>>2)&3)
  const int bid = blockIdx.x;
  const int g  = bid & 7;
  const int s  = bid >> 3;
  const int bx = (g << 2) + (s & 3);
  const int by = ((s >> 4) << 2) + ((s >> 2) & 3);
  const int m0 = by << 7;
  const int n0 = bx << 7;   // linear row block in permuted W
  const int h0 = bx << 5;   // 32 h per block

  // epilogue lane mapping + bias preload (latency hidden by K-loop)
  const int er = (lane >> 4) << 2;
  const int ec = lane & 15;
  const int h  = h0 + (wn << 4) + ec;
  float bias[4];
#pragma unroll
  for (int j = 0; j < 4; ++j) bias[j] = bi[j * 1024 + h] + bh[j * 1024 + h];

  // ---- staging: uniform base (SGPR) + ONE shared per-lane offset ----
  const int sr = tid >> 3;                              // LDS row 0..31 (+p*32)
  const int cs = ((tid & 7) ^ (sr & 7)) << 4;           // XOR-swizzled source chunk
  const unsigned voff = (unsigned)sr * 4096u + (unsigned)cs;  // per-lane, invariant
  const char* aBase = (const char*)A  + (size_t)m0 * 4096;    // row = 4096 B
  const char* bBase = (const char*)Bt + (size_t)n0 * 4096;
  char* aD = AsB + tid * 16;
  char* bD = BsB + tid * 16;

  floatx4 acc[4][4] = {};
  // LDS fragment bases (loop-invariant; f*16 rows -> +f*2048 immediate)
  const int rA = (wm << 6) + (lane & 15);
  const int rB = (wn << 6) + (lane & 15);
  const int keyc = lane & 7;
  const int kq   = lane >> 4;
  const char* aF0 = AsB + rA * 128 + ((kq ^ keyc) << 4);
  const char* aF1 = AsB + rA * 128 + (((4 + kq) ^ keyc) << 4);
  const char* bF0 = BsB + rB * 128 + ((kq ^ keyc) << 4);
  const char* bF1 = BsB + rB * 128 + (((4 + kq) ^ keyc) << 4);

  for (int ks = 0; ks < K; ks += 64) {
    const char* aIt = aBase + ks * 2;   // uniform
    const char* bIt = bBase + ks * 2;   // uniform
#pragma unroll
    for (int p = 0; p < 4; ++p) gl_lds16(aIt + p * 131072 + voff, aD + p * 4096);
#pragma unroll
    for (int p = 0; p < 4; ++p) gl_lds16(bIt + p * 131072 + voff, bD + p * 4096);
    __syncthreads();
    {
      short8 af[4], bfr[4];
#pragma unroll
      for (int f = 0; f < 4; ++f) {
        af[f]  = *(const short8*)(aF0 + f * 2048);
        bfr[f] = *(const short8*)(bF0 + f * 2048);
      }
#pragma unroll
      for (int i = 0; i < 4; ++i)
#pragma unroll
        for (int j = 0; j < 4; ++j)
          acc[i][j] = __builtin_amdgcn_mfma_f32_16x16x32_bf16(af[i], bfr[j], acc[i][j], 0, 0, 0);
    }
    {
      short8 af[4], bfr[4];
#pragma unroll
      for (int f = 0; f < 4; ++f) {
        af[f]  = *(const short8*)(aF1 + f * 2048);
        bfr[f] = *(const short8*)(bF1 + f * 2048);
      }
#pragma unroll
      for (int i = 0; i < 4; ++i)
#pragma unroll
        for (int j = 0; j < 4; ++j)
          acc[i][j] = __builtin_amdgcn_mfma_f32_16x16x32_bf16(af[i], bfr[j], acc[i][j], 0, 0, 0);
    }
    __syncthreads();
  }

  // ---- fused LSTM epilogue: batch ct loads (one overlapped miss window),
  // then lane-local gates (j == gate) ----
  float cv[4][4];
#pragma unroll
  for (int i = 0; i < 4; ++i)
#pragma unroll
    for (int rg = 0; rg < 4; ++rg) {
      int row = m0 + (wm << 6) + i * 16 + er + rg;
      cv[i][rg] = ct[(size_t)row * 1024 + h];
    }
#pragma unroll
  for (int i = 0; i < 4; ++i) {
#pragma unroll
    for (int rg = 0; rg < 4; ++rg) {
      int row = m0 + (wm << 6) + i * 16 + er + rg;
      size_t o = (size_t)row * 1024 + h;
      float iv = sigm(acc[i][0][rg] + bias[0]);
      float fv = sigm(acc[i][1][rg] + bias[1]);
      float gv = tanhx(acc[i][2][rg] + bias[2]);
      float ov = sigm(acc[i][3][rg] + bias[3]);
      float cn = fv * cv[i][rg] + iv * gv;
      out[o] = ov * tanhx(cn);
      out[4194304 + o] = cn;
    }
  }
}

// ---------------------------------------------------------------------------
extern "C" void kernel_launch(void* const* d_in, const int* in_sizes, int n_in,
                              void* d_out, int out_size, void* d_ws, size_t ws_size,
                              hipStream_t stream) {
  const float* x  = (const float*)d_in[0];
  const float* ht = (const float*)d_in[1];
  const float* ct = (const float*)d_in[2];
  const float* wi = (const float*)d_in[3];
  const float* wh = (const float*)d_in[4];
  const float* bi = (const float*)d_in[5];
  const float* bh = (const float*)d_in[6];
  float* out = (float*)d_out;

  char* ws = (char*)d_ws;
  unsigned short* Abf = (unsigned short*)ws;                 // 16 MiB
  unsigned short* Wbf = (unsigned short*)(ws + (16u << 20)); // 16 MiB

  pack_all<<<6144, 256, 0, stream>>>(x, ht, wi, wh, Abf, Wbf);
  gemm_lstm<<<1024, 256, 0, stream>>>(Abf, Wbf, ct, bi, bh, out);
}